// Round 1
// baseline (169.573 us; speedup 1.0000x reference)
//
#include <hip/hip_runtime.h>
#include <hip/hip_bf16.h>
#include <cstdint>

// Problem constants
#define B_DIM 2048
#define H_DIM 1024
#define K_DIM 2048   // 2*H  (input | hidden)
#define N_DIM 4096   // 4*H  (gates, interleaved n' = 4*h + gate)

typedef unsigned short u16;
typedef __attribute__((ext_vector_type(8))) short bf16x8;
typedef __attribute__((ext_vector_type(8))) unsigned short u16x8;
typedef __attribute__((ext_vector_type(4))) float f32x4;

__device__ __forceinline__ u16 f2bf(float f) {
    unsigned int u = __float_as_uint(f);
    u += 0x7FFFu + ((u >> 16) & 1u);   // round-to-nearest-even
    return (u16)(u >> 16);
}

__device__ __forceinline__ float sigmoid_f(float x) {
    return 1.0f / (1.0f + __expf(-x));
}

// tanh via exp, saturating form (no inf/inf NaN at large |x|)
__device__ __forceinline__ float tanh_f(float x) {
    float e = __expf(2.0f * x);
    return 1.0f - 2.0f / (e + 1.0f);
}

// async global->LDS 16B per lane. LDS dest is wave-uniform base + lane*16.
__device__ __forceinline__ void async16(const u16* g, u16* l) {
    __builtin_amdgcn_global_load_lds(
        (const __attribute__((address_space(1))) unsigned int*)g,
        (__attribute__((address_space(3))) unsigned int*)l,
        16, 0, 0);
}

// ---------------------------------------------------------------------------
// Kernel 1: all packing in ONE launch.  (unchanged from verified R-prev)
// Region A (blocks 0..4095):        A = [input|hidden] bf16 2048x2048
// Region B (blocks 4096..8191):     Bt[n'][k], n' = 4h+g (f,i,o,c)
// Region bias (blocks 8192..8207):  bias_il[4h+g] = b_g[h]
// ---------------------------------------------------------------------------
__global__ __launch_bounds__(256) void pack_all(
    const float* __restrict__ input, const float* __restrict__ hidden,
    const float* __restrict__ w_f, const float* __restrict__ w_i,
    const float* __restrict__ w_o, const float* __restrict__ w_c,
    const float* __restrict__ u_f, const float* __restrict__ u_i,
    const float* __restrict__ u_o, const float* __restrict__ u_c,
    const float* __restrict__ b1, const float* __restrict__ b2,
    const float* __restrict__ b3, const float* __restrict__ b4,
    u16* __restrict__ A, u16* __restrict__ Bt, float* __restrict__ bias_il) {
    __shared__ float tile[32][65];
    const int blk = blockIdx.x;
    const int t = threadIdx.x;

    if (blk < 4096) {
        // ---- pack_A ----
        int idx = (blk * 256 + t) * 4;
        int m = idx >> 11;
        int k = idx & (K_DIM - 1);
        const float* src = (k < H_DIM) ? (input + (size_t)m * H_DIM + k)
                                       : (hidden + (size_t)m * H_DIM + (k - H_DIM));
        float4 v = *(const float4*)src;
        ushort4 o;
        o.x = f2bf(v.x); o.y = f2bf(v.y); o.z = f2bf(v.z); o.w = f2bf(v.w);
        *(ushort4*)(A + idx) = o;
    } else if (blk < 8192) {
        // ---- pack_B: 32h x 64k tile transpose ----
        int b2i = blk - 4096;
        int z = b2i >> 9;
        int rem = b2i & 511;
        int hx = rem & 31;
        int ky = rem >> 5;
        const float* M;
        switch (z) {
            case 0: M = w_f; break;
            case 1: M = w_i; break;
            case 2: M = w_o; break;
            case 3: M = w_c; break;
            case 4: M = u_f; break;
            case 5: M = u_i; break;
            case 6: M = u_o; break;
            default: M = u_c; break;
        }
        const int g = z & 3;
        const int half = z >> 2;
        const int h0 = hx * 32;
        const int k0 = ky * 64;
#pragma unroll
        for (int it = 0; it < 2; it++) {
            int kl = (t >> 3) + it * 32;
            int hl = (t & 7) * 4;
            float4 v = *(const float4*)(M + (size_t)(k0 + kl) * H_DIM + h0 + hl);
            tile[hl + 0][kl] = v.x;
            tile[hl + 1][kl] = v.y;
            tile[hl + 2][kl] = v.z;
            tile[hl + 3][kl] = v.w;
        }
        __syncthreads();
        int hl = t >> 3;
        int ko = (t & 7) * 8;
        u16x8 o;
#pragma unroll
        for (int q = 0; q < 8; q++) o[q] = f2bf(tile[hl][ko + q]);
        size_t n = 4 * (size_t)(h0 + hl) + g;
        *(u16x8*)(Bt + n * K_DIM + half * H_DIM + k0 + ko) = o;
    } else {
        // ---- pack_bias ----
        int idx = (blk - 8192) * 256 + t;
        int h = idx >> 2, g = idx & 3;
        const float* b = (g == 0) ? b1 : (g == 1) ? b2 : (g == 2) ? b3 : b4;
        bias_il[idx] = b[h];
    }
}

// ---------------------------------------------------------------------------
// Kernel 2: fused GEMM + LSTM epilogue.
// BM=BN=128 (grid 32x16=512 blocks, 2 blocks/CU), BK=32, FOUR-slot LDS ring
// (4 x (A 8KB | B 8KB) = 64KB), prefetch 3 K-tiles ahead with COUNTED
// s_waitcnt vmcnt(12) + raw s_barrier (no compiler vmcnt(0) drain -- the
// m97-structure ~20% stall).  T2 both-sides XOR swizzle: byte^=((row&6)<<3),
// realized as pre-swizzled GLOBAL source k-offset (gload_lds dest stays
// linear, rule #21) + the same XOR folded into the constant per-lane ds_read
// offsets -> each quarter-wave's 16 lanes cover all 8 bank groups 2-way
// (free, m136).  T5 setprio around the MFMA cluster.
// Wave decomposition (2x2, per-wave 64x64), fragment math, and the fused
// epilogue are IDENTICAL to the previous verified kernel.
// ---------------------------------------------------------------------------
#define BM 128
#define BN 128

__global__ __launch_bounds__(256, 2) void gemm_fused(
    const u16* __restrict__ A, const u16* __restrict__ Bt,
    const float* __restrict__ bias_il, const float* __restrict__ pre_cell,
    const float* __restrict__ mask, float* __restrict__ out) {
    __shared__ char smem[65536];           // 4 slots x 16KB (A 8KB | B 8KB)
    float* et = (float*)smem;              // epilogue reuse: [128][33] f32

    const int t = threadIdx.x;
    const int w = t >> 6, l = t & 63;
    const int m0 = blockIdx.y * BM;
    const int n0 = blockIdx.x * BN;
    const int wr = w >> 1;    // wave row in 2x2
    const int wc = w & 1;     // wave col
    const int lrow = l & 15;
    const int quad = l >> 4;

    // ---- staging addresses (pre-swizzled global source, linear LDS dest) --
    // thread t covers slab row srow=t>>2 (and srow+64 on 2nd issue), 16B at
    // k-offset (t&3)*8 u16, XOR'd by ((srow&6)<<2) u16 == ((srow&6)<<3) bytes.
    // (srow+64)&6 == srow&6, so one swizzled offset serves both issues.
    const int srow = t >> 2;                                // 0..63
    const int skswz = ((t & 3) * 8) ^ ((srow & 6) << 2);    // u16 units
    const u16* AgS0 = A + (size_t)(m0 + srow) * K_DIM + skswz;
    const u16* AgS1 = AgS0 + (size_t)64 * K_DIM;
    const u16* BgS0 = Bt + (size_t)(n0 + srow) * K_DIM + skswz;
    const u16* BgS1 = BgS0 + (size_t)64 * K_DIM;

    // ---- fragment read offsets (same rows as before + matching XOR) ------
    // row = wr*64 + i*16 + lrow: bits[2:1] of row come only from lrow, so the
    // XOR value is a per-lane constant and is addition-carry-free.
    const int swzf = (quad * 8) ^ ((lrow & 6) << 2);        // u16 units
    const int foA = (wr * 64 + lrow) * 32 + swzf;
    const int foB = (wc * 64 + lrow) * 32 + swzf;

    // acc init = bias (constant down a column) -- do this BEFORE staging so
    // the compiler's bias-load waits retire before the gload_lds window opens.
    f32x4 acc[4][4];
#pragma unroll
    for (int j = 0; j < 4; j++) {
        float bv = bias_il[n0 + wc * 64 + j * 16 + lrow];
#pragma unroll
        for (int i = 0; i < 4; i++) acc[i][j] = (f32x4){bv, bv, bv, bv};
    }

    // ---- prologue: prefetch K-tiles 0,1,2 (12 gload_lds in flight) -------
#pragma unroll
    for (int p = 0; p < 3; ++p) {
        u16* As_ = (u16*)(smem + p * 16384);
        u16* Bs_ = As_ + 4096;
        const int ko_ = p * 32;
        async16(AgS0 + ko_, As_ + t * 8);
        async16(AgS1 + ko_, As_ + 2048 + t * 8);
        async16(BgS0 + ko_, Bs_ + t * 8);
        async16(BgS1 + ko_, Bs_ + 2048 + t * 8);
    }

    // One K-step: optionally stage tile kt+3 into slot (kt+3)&3 (that slot
    // was last read at iter kt-1, whose end barrier all waves have passed),
    // wait own oldest staging batch (counted vmcnt), publish via barrier,
    // then 8 ds_read_b128 + 16 MFMA on slot kt&3.
#define KSTEP(kt, DO_STAGE, VM)                                             \
    {                                                                       \
        if (DO_STAGE) {                                                     \
            u16* As_ = (u16*)(smem + (((kt) + 3) & 3) * 16384);             \
            u16* Bs_ = As_ + 4096;                                          \
            const int ko_ = ((kt) + 3) * 32;                                \
            async16(AgS0 + ko_, As_ + t * 8);                               \
            async16(AgS1 + ko_, As_ + 2048 + t * 8);                        \
            async16(BgS0 + ko_, Bs_ + t * 8);                               \
            async16(BgS1 + ko_, Bs_ + 2048 + t * 8);                        \
        }                                                                   \
        asm volatile("s_waitcnt vmcnt(" #VM ")" ::: "memory");              \
        __builtin_amdgcn_s_barrier();                                       \
        asm volatile("" ::: "memory");                                      \
        const u16* As = (const u16*)(smem + ((kt) & 3) * 16384);            \
        const u16* Bs = As + 4096;                                          \
        bf16x8 af[4], bf[4];                                                \
        _Pragma("unroll") for (int i = 0; i < 4; i++)                       \
            af[i] = *(const bf16x8*)(As + foA + i * 512);                   \
        _Pragma("unroll") for (int j = 0; j < 4; j++)                       \
            bf[j] = *(const bf16x8*)(Bs + foB + j * 512);                   \
        __builtin_amdgcn_s_setprio(1);                                      \
        _Pragma("unroll") for (int i = 0; i < 4; i++)                       \
            _Pragma("unroll") for (int j = 0; j < 4; j++)                   \
                acc[i][j] = __builtin_amdgcn_mfma_f32_16x16x32_bf16(        \
                    af[i], bf[j], acc[i][j], 0, 0, 0);                      \
        __builtin_amdgcn_s_setprio(0);                                      \
        asm volatile("" ::: "memory");                                      \
        __builtin_amdgcn_s_barrier();                                       \
    }

    // 64 K-tiles total. Tiles 3..63 staged inside the loop; in-flight window
    // is 3 tiles x 4 issues -> vmcnt(12) in steady state, 8/4/0 in the tail.
    for (int kt = 0; kt < 60; kt += 4) {
        KSTEP(kt + 0, true, 12);
        KSTEP(kt + 1, true, 12);
        KSTEP(kt + 2, true, 12);
        KSTEP(kt + 3, true, 12);
    }
    KSTEP(60, true, 12);
    KSTEP(61, false, 8);
    KSTEP(62, false, 4);
    KSTEP(63, false, 0);
#undef KSTEP

    // ---- fused LSTM epilogue (unchanged, verified) ----
    // C/D layout: col = lane&15, row = quad*4 + reg  [m89/m91-verified]
    const int row = t >> 1;     // 0..127
    const int half = t & 1;     // 0 -> wc=0 cols, 1 -> wc=1 cols
    const size_t orow = (size_t)(m0 + row) * H_DIM;

    // prefetch epilogue operands now; latency hides under the 4 LDS phases
    float4 pc[4], mk[4];
#pragma unroll
    for (int j = 0; j < 4; j++) {
        const int hg0 = (n0 >> 2) + half * 16 + j * 4;
        pc[j] = *(const float4*)(pre_cell + orow + hg0);
        mk[j] = *(const float4*)(mask + orow + hg0);
    }

#pragma unroll
    for (int j = 0; j < 4; j++) {
        __syncthreads();        // et aliases staging; prior reads complete
#pragma unroll
        for (int i = 0; i < 4; i++)
#pragma unroll
            for (int r = 0; r < 4; r++)
                et[(wr * 64 + i * 16 + quad * 4 + r) * 33 + wc * 16 + lrow] =
                    acc[i][j][r];
        __syncthreads();
        const int hg0 = (n0 >> 2) + half * 16 + j * 4;
        const float* ep = et + row * 33 + half * 16;  // 4h x 4gates = 16 f32
        const float* ppc = (const float*)&pc[j];
        const float* pmk = (const float*)&mk[j];
        float4 oh, oc;
        float* poh = (float*)&oh;
        float* poc = (float*)&oc;
#pragma unroll
        for (int q = 0; q < 4; q++) {
            float fv = sigmoid_f(ep[4 * q + 0]);
            float iv = sigmoid_f(ep[4 * q + 1]);
            float ov = sigmoid_f(ep[4 * q + 2]);
            float gv = tanh_f(ep[4 * q + 3]);
            float cv = ppc[q] * fv + iv * gv;
            poc[q] = cv;
            poh[q] = ov * tanh_f(cv) * pmk[q];
        }
        *(float4*)(out + orow + hg0) = oh;
        *(float4*)(out + (size_t)B_DIM * H_DIM + orow + hg0) = oc;
    }
}

// ---------------------------------------------------------------------------
extern "C" void kernel_launch(void* const* d_in, const int* in_sizes, int n_in,
                              void* d_out, int out_size, void* d_ws, size_t ws_size,
                              hipStream_t stream) {
    const float* input    = (const float*)d_in[0];
    const float* hidden   = (const float*)d_in[1];
    const float* pre_cell = (const float*)d_in[2];
    const float* w_i = (const float*)d_in[3];
    const float* w_f = (const float*)d_in[4];
    const float* w_o = (const float*)d_in[5];
    const float* w_c = (const float*)d_in[6];
    const float* u_i = (const float*)d_in[7];
    const float* u_f = (const float*)d_in[8];
    const float* u_o = (const float*)d_in[9];
    const float* u_c = (const float*)d_in[10];
    const float* b1  = (const float*)d_in[11];
    const float* b2  = (const float*)d_in[12];
    const float* b3  = (const float*)d_in[13];
    const float* b4  = (const float*)d_in[14];
    const float* mask = (const float*)d_in[15];
    float* out = (float*)d_out;

    // workspace: A bf16 (8 MiB) | Bt bf16 (16 MiB) | bias_il (16 KiB)
    char* ws = (char*)d_ws;
    u16*   A       = (u16*)ws;
    u16*   Bt      = (u16*)(ws + (size_t)8 * 1024 * 1024);
    float* bias_il = (float*)(ws + (size_t)24 * 1024 * 1024);

    pack_all<<<dim3(4096 + 4096 + 16), dim3(256), 0, stream>>>(
        input, hidden, w_f, w_i, w_o, w_c, u_f, u_i, u_o, u_c,
        b1, b2, b3, b4, A, Bt, bias_il);
    gemm_fused<<<dim3(N_DIM / BN, B_DIM / BM), dim3(256), 0, stream>>>(
        A, Bt, bias_il, pre_cell, mask, out);
}

// Round 2
// 169.181 us; speedup vs baseline: 1.0023x; 1.0023x over previous
//
#include <hip/hip_runtime.h>
#include <hip/hip_bf16.h>
#include <cstdint>

// Problem constants
#define B_DIM 2048
#define H_DIM 1024
#define K_DIM 2048   // 2*H  (input | hidden)
#define N_DIM 4096   // 4*H  (gates, interleaved n' = 4*h + gate)

typedef unsigned short u16;
typedef __attribute__((ext_vector_type(8))) short bf16x8;
typedef __attribute__((ext_vector_type(8))) unsigned short u16x8;
typedef __attribute__((ext_vector_type(4))) float f32x4;

__device__ __forceinline__ u16 f2bf(float f) {
    unsigned int u = __float_as_uint(f);
    u += 0x7FFFu + ((u >> 16) & 1u);   // round-to-nearest-even
    return (u16)(u >> 16);
}

__device__ __forceinline__ float sigmoid_f(float x) {
    return 1.0f / (1.0f + __expf(-x));
}

// tanh via exp, saturating form (no inf/inf NaN at large |x|)
__device__ __forceinline__ float tanh_f(float x) {
    float e = __expf(2.0f * x);
    return 1.0f - 2.0f / (e + 1.0f);
}

// async global->LDS 16B per lane. LDS dest is wave-uniform base + lane*16.
__device__ __forceinline__ void async16(const u16* g, u16* l) {
    __builtin_amdgcn_global_load_lds(
        (const __attribute__((address_space(1))) unsigned int*)g,
        (__attribute__((address_space(3))) unsigned int*)l,
        16, 0, 0);
}

// ---------------------------------------------------------------------------
// Kernel 1: all packing in ONE launch.  (unchanged, verified)
// Region A (blocks 0..4095):        A = [input|hidden] bf16 2048x2048
// Region B (blocks 4096..8191):     Bt[n'][k], n' = 4h+g (f,i,o,c)
// Region bias (blocks 8192..8207):  bias_il[4h+g] = b_g[h]
// ---------------------------------------------------------------------------
__global__ __launch_bounds__(256) void pack_all(
    const float* __restrict__ input, const float* __restrict__ hidden,
    const float* __restrict__ w_f, const float* __restrict__ w_i,
    const float* __restrict__ w_o, const float* __restrict__ w_c,
    const float* __restrict__ u_f, const float* __restrict__ u_i,
    const float* __restrict__ u_o, const float* __restrict__ u_c,
    const float* __restrict__ b1, const float* __restrict__ b2,
    const float* __restrict__ b3, const float* __restrict__ b4,
    u16* __restrict__ A, u16* __restrict__ Bt, float* __restrict__ bias_il) {
    __shared__ float tile[32][65];
    const int blk = blockIdx.x;
    const int t = threadIdx.x;

    if (blk < 4096) {
        // ---- pack_A ----
        int idx = (blk * 256 + t) * 4;
        int m = idx >> 11;
        int k = idx & (K_DIM - 1);
        const float* src = (k < H_DIM) ? (input + (size_t)m * H_DIM + k)
                                       : (hidden + (size_t)m * H_DIM + (k - H_DIM));
        float4 v = *(const float4*)src;
        ushort4 o;
        o.x = f2bf(v.x); o.y = f2bf(v.y); o.z = f2bf(v.z); o.w = f2bf(v.w);
        *(ushort4*)(A + idx) = o;
    } else if (blk < 8192) {
        // ---- pack_B: 32h x 64k tile transpose ----
        int b2i = blk - 4096;
        int z = b2i >> 9;
        int rem = b2i & 511;
        int hx = rem & 31;
        int ky = rem >> 5;
        const float* M;
        switch (z) {
            case 0: M = w_f; break;
            case 1: M = w_i; break;
            case 2: M = w_o; break;
            case 3: M = w_c; break;
            case 4: M = u_f; break;
            case 5: M = u_i; break;
            case 6: M = u_o; break;
            default: M = u_c; break;
        }
        const int g = z & 3;
        const int half = z >> 2;
        const int h0 = hx * 32;
        const int k0 = ky * 64;
#pragma unroll
        for (int it = 0; it < 2; it++) {
            int kl = (t >> 3) + it * 32;
            int hl = (t & 7) * 4;
            float4 v = *(const float4*)(M + (size_t)(k0 + kl) * H_DIM + h0 + hl);
            tile[hl + 0][kl] = v.x;
            tile[hl + 1][kl] = v.y;
            tile[hl + 2][kl] = v.z;
            tile[hl + 3][kl] = v.w;
        }
        __syncthreads();
        int hl = t >> 3;
        int ko = (t & 7) * 8;
        u16x8 o;
#pragma unroll
        for (int q = 0; q < 8; q++) o[q] = f2bf(tile[hl][ko + q]);
        size_t n = 4 * (size_t)(h0 + hl) + g;
        *(u16x8*)(Bt + n * K_DIM + half * H_DIM + k0 + ko) = o;
    } else {
        // ---- pack_bias ----
        int idx = (blk - 8192) * 256 + t;
        int h = idx >> 2, g = idx & 3;
        const float* b = (g == 0) ? b1 : (g == 1) ? b2 : (g == 2) ? b3 : b4;
        bias_il[idx] = b[h];
    }
}

// ---------------------------------------------------------------------------
// Kernel 2: fused GEMM + LSTM epilogue.
// BM=BN=128 (grid 32x16=512, 2 blocks/CU), BK=32, FOUR-slot LDS ring.
// R1 post-mortem: T2 swizzle verified (-17x bank conflicts) but the
// 2-barrier-per-KSTEP schedule quadrupled barrier count vs R0 (128 vs 32)
// and cost +6us.  R2: ONE barrier per KSTEP.  The publish barrier also
// protects slot reuse because staging of slot (kt+3)&3 == (kt-1)&3 is moved
// AFTER it: every wave passing barrier kt has already consumed slot
// (kt-1)&3 (its ds_reads completed before its MFMAs issued, which precede
// the barrier in program order).  Per-KSTEP shape:
//     vmcnt(8) -> s_barrier -> stage kt+3 -> 8 ds_read + 16 MFMA on kt
// Depth-3 prefetch: 12 loads in flight, wait leaves 8 outstanding -- the
// counted-vmcnt never drains to 0 in the main loop (T4).  T5 setprio kept.
// ---------------------------------------------------------------------------
#define BM 128
#define BN 128

__global__ __launch_bounds__(256, 2) void gemm_fused(
    const u16* __restrict__ A, const u16* __restrict__ Bt,
    const float* __restrict__ bias_il, const float* __restrict__ pre_cell,
    const float* __restrict__ mask, float* __restrict__ out) {
    __shared__ char smem[65536];           // 4 slots x 16KB (A 8KB | B 8KB)
    float* et = (float*)smem;              // epilogue reuse: [128][33] f32

    const int t = threadIdx.x;
    const int w = t >> 6, l = t & 63;
    const int m0 = blockIdx.y * BM;
    const int n0 = blockIdx.x * BN;
    const int wr = w >> 1;    // wave row in 2x2
    const int wc = w & 1;     // wave col
    const int lrow = l & 15;
    const int quad = l >> 4;

    // ---- staging addresses (pre-swizzled global source, linear LDS dest) --
    // thread t covers slab row srow=t>>2 (and srow+64 on 2nd issue), 16B at
    // k-offset (t&3)*8 u16, XOR'd by ((srow&6)<<2) u16 == ((srow&6)<<3) bytes.
    // (srow+64)&6 == srow&6, so one swizzled offset serves both issues.
    const int srow = t >> 2;                                // 0..63
    const int skswz = ((t & 3) * 8) ^ ((srow & 6) << 2);    // u16 units
    const u16* AgS0 = A + (size_t)(m0 + srow) * K_DIM + skswz;
    const u16* AgS1 = AgS0 + (size_t)64 * K_DIM;
    const u16* BgS0 = Bt + (size_t)(n0 + srow) * K_DIM + skswz;
    const u16* BgS1 = BgS0 + (size_t)64 * K_DIM;

    // ---- fragment read offsets (same rows + matching XOR) ----------------
    // row = wr*64 + i*16 + lrow: bits[2:1] of row come only from lrow, so the
    // XOR value is a per-lane constant and is addition-carry-free.
    const int swzf = (quad * 8) ^ ((lrow & 6) << 2);        // u16 units
    const int foA = (wr * 64 + lrow) * 32 + swzf;
    const int foB = (wc * 64 + lrow) * 32 + swzf;

    // acc init = bias (constant down a column)
    f32x4 acc[4][4];
#pragma unroll
    for (int j = 0; j < 4; j++) {
        float bv = bias_il[n0 + wc * 64 + j * 16 + lrow];
#pragma unroll
        for (int i = 0; i < 4; i++) acc[i][j] = (f32x4){bv, bv, bv, bv};
    }
    // retire the bias vector-load so manual vmcnt counting below is exact
    asm volatile("s_waitcnt vmcnt(0)" ::: "memory");

#define STAGE(p)                                                            \
    {                                                                       \
        u16* As_ = (u16*)(smem + ((p) & 3) * 16384);                        \
        u16* Bs_ = As_ + 4096;                                              \
        const int ko_ = (p) * 32;                                           \
        async16(AgS0 + ko_, As_ + t * 8);                                   \
        async16(AgS1 + ko_, As_ + 2048 + t * 8);                            \
        async16(BgS0 + ko_, Bs_ + t * 8);                                   \
        async16(BgS1 + ko_, Bs_ + 2048 + t * 8);                            \
    }

    // ---- prologue: prefetch K-tiles 0,1,2 (12 gload_lds in flight) -------
    STAGE(0); STAGE(1); STAGE(2);

    // One KSTEP: wait own oldest staging batch (counted vmcnt -> slab kt
    // landed), publish via single barrier, stage slab kt+3 into slot
    // (kt+3)&3 (== (kt-1)&3, free: all waves consumed it before barrier),
    // then 8 ds_read_b128 + 16 MFMA on slot kt&3.
#define KSTEP(kt, DO_STAGE, VM)                                             \
    {                                                                       \
        asm volatile("s_waitcnt vmcnt(" #VM ")" ::: "memory");              \
        __builtin_amdgcn_s_barrier();                                       \
        asm volatile("" ::: "memory");                                      \
        if (DO_STAGE) STAGE((kt) + 3);                                      \
        const u16* As = (const u16*)(smem + ((kt) & 3) * 16384);            \
        const u16* Bs = As + 4096;                                          \
        bf16x8 af[4], bf[4];                                                \
        _Pragma("unroll") for (int i = 0; i < 4; i++)                       \
            af[i] = *(const bf16x8*)(As + foA + i * 512);                   \
        _Pragma("unroll") for (int j = 0; j < 4; j++)                       \
            bf[j] = *(const bf16x8*)(Bs + foB + j * 512);                   \
        __builtin_amdgcn_s_setprio(1);                                      \
        _Pragma("unroll") for (int i = 0; i < 4; i++)                       \
            _Pragma("unroll") for (int j = 0; j < 4; j++)                   \
                acc[i][j] = __builtin_amdgcn_mfma_f32_16x16x32_bf16(        \
                    af[i], bf[j], acc[i][j], 0, 0, 0);                      \
        __builtin_amdgcn_s_setprio(0);                                      \
        asm volatile("" ::: "memory");                                      \
    }

    // 64 K-tiles. Slab kt+3 staged at KSTEP kt (kt<=60).  At KSTEP kt's
    // wait, worst-case outstanding = slabs kt,kt+1,kt+2 (12 loads); slab kt
    // ready at vmcnt(8).  Tail: 62 -> vmcnt(4), 63 -> vmcnt(0).
    for (int kt = 0; kt < 60; kt += 4) {
        KSTEP(kt + 0, true, 8);
        KSTEP(kt + 1, true, 8);
        KSTEP(kt + 2, true, 8);
        KSTEP(kt + 3, true, 8);
    }
    KSTEP(60, true, 8);
    KSTEP(61, false, 8);
    KSTEP(62, false, 4);
    KSTEP(63, false, 0);
#undef KSTEP
#undef STAGE

    // ---- fused LSTM epilogue (unchanged, verified) ----
    // C/D layout: col = lane&15, row = quad*4 + reg  [m89/m91-verified]
    const int row = t >> 1;     // 0..127
    const int half = t & 1;     // 0 -> wc=0 cols, 1 -> wc=1 cols
    const size_t orow = (size_t)(m0 + row) * H_DIM;

    // prefetch epilogue operands now; latency hides under the 4 LDS phases
    float4 pc[4], mk[4];
#pragma unroll
    for (int j = 0; j < 4; j++) {
        const int hg0 = (n0 >> 2) + half * 16 + j * 4;
        pc[j] = *(const float4*)(pre_cell + orow + hg0);
        mk[j] = *(const float4*)(mask + orow + hg0);
    }

#pragma unroll
    for (int j = 0; j < 4; j++) {
        __syncthreads();        // et aliases staging; prior reads complete
#pragma unroll
        for (int i = 0; i < 4; i++)
#pragma unroll
            for (int r = 0; r < 4; r++)
                et[(wr * 64 + i * 16 + quad * 4 + r) * 33 + wc * 16 + lrow] =
                    acc[i][j][r];
        __syncthreads();
        const int hg0 = (n0 >> 2) + half * 16 + j * 4;
        const float* ep = et + row * 33 + half * 16;  // 4h x 4gates = 16 f32
        const float* ppc = (const float*)&pc[j];
        const float* pmk = (const float*)&mk[j];
        float4 oh, oc;
        float* poh = (float*)&oh;
        float* poc = (float*)&oc;
#pragma unroll
        for (int q = 0; q < 4; q++) {
            float fv = sigmoid_f(ep[4 * q + 0]);
            float iv = sigmoid_f(ep[4 * q + 1]);
            float ov = sigmoid_f(ep[4 * q + 2]);
            float gv = tanh_f(ep[4 * q + 3]);
            float cv = ppc[q] * fv + iv * gv;
            poc[q] = cv;
            poh[q] = ov * tanh_f(cv) * pmk[q];
        }
        *(float4*)(out + orow + hg0) = oh;
        *(float4*)(out + (size_t)B_DIM * H_DIM + orow + hg0) = oc;
    }
}

// ---------------------------------------------------------------------------
extern "C" void kernel_launch(void* const* d_in, const int* in_sizes, int n_in,
                              void* d_out, int out_size, void* d_ws, size_t ws_size,
                              hipStream_t stream) {
    const float* input    = (const float*)d_in[0];
    const float* hidden   = (const float*)d_in[1];
    const float* pre_cell = (const float*)d_in[2];
    const float* w_i = (const float*)d_in[3];
    const float* w_f = (const float*)d_in[4];
    const float* w_o = (const float*)d_in[5];
    const float* w_c = (const float*)d_in[6];
    const float* u_i = (const float*)d_in[7];
    const float* u_f = (const float*)d_in[8];
    const float* u_o = (const float*)d_in[9];
    const float* u_c = (const float*)d_in[10];
    const float* b1  = (const float*)d_in[11];
    const float* b2  = (const float*)d_in[12];
    const float* b3  = (const float*)d_in[13];
    const float* b4  = (const float*)d_in[14];
    const float* mask = (const float*)d_in[15];
    float* out = (float*)d_out;

    // workspace: A bf16 (8 MiB) | Bt bf16 (16 MiB) | bias_il (16 KiB)
    char* ws = (char*)d_ws;
    u16*   A       = (u16*)ws;
    u16*   Bt      = (u16*)(ws + (size_t)8 * 1024 * 1024);
    float* bias_il = (float*)(ws + (size_t)24 * 1024 * 1024);

    pack_all<<<dim3(4096 + 4096 + 16), dim3(256), 0, stream>>>(
        input, hidden, w_f, w_i, w_o, w_c, u_f, u_i, u_o, u_c,
        b1, b2, b3, b4, A, Bt, bias_il);
    gemm_fused<<<dim3(N_DIM / BN, B_DIM / BM), dim3(256), 0, stream>>>(
        A, Bt, bias_il, pre_cell, mask, out);
}

// Round 3
// 168.800 us; speedup vs baseline: 1.0046x; 1.0023x over previous
//
#include <hip/hip_runtime.h>
#include <hip/hip_bf16.h>
#include <cstdint>

// Problem constants
#define B_DIM 2048
#define H_DIM 1024
#define K_DIM 2048   // 2*H  (input | hidden)
#define N_DIM 4096   // 4*H  (gates, interleaved n' = 4*h + gate)

typedef unsigned short u16;
typedef __attribute__((ext_vector_type(8))) short bf16x8;
typedef __attribute__((ext_vector_type(8))) unsigned short u16x8;
typedef __attribute__((ext_vector_type(4))) float f32x4;

__device__ __forceinline__ u16 f2bf(float f) {
    unsigned int u = __float_as_uint(f);
    u += 0x7FFFu + ((u >> 16) & 1u);   // round-to-nearest-even
    return (u16)(u >> 16);
}

__device__ __forceinline__ float sigmoid_f(float x) {
    return 1.0f / (1.0f + __expf(-x));
}

// tanh via exp, saturating form (no inf/inf NaN at large |x|)
__device__ __forceinline__ float tanh_f(float x) {
    float e = __expf(2.0f * x);
    return 1.0f - 2.0f / (e + 1.0f);
}

// async global->LDS 16B per lane. LDS dest is wave-uniform base + lane*16.
__device__ __forceinline__ void async16(const u16* g, u16* l) {
    __builtin_amdgcn_global_load_lds(
        (const __attribute__((address_space(1))) unsigned int*)g,
        (__attribute__((address_space(3))) unsigned int*)l,
        16, 0, 0);
}

// ---------------------------------------------------------------------------
// Kernel 1: all packing in ONE launch.
// Region A (blocks 0..4095):        A = [input|hidden] bf16 2048x2048
// Region B (blocks 4096..8191):     Bf = FRAGMENT-READY B
//     Bf[ntile][kt][(k8*16+nrow)*8 + ko], ntile=n'>>4, nrow=n'&15,
//     kt=k>>5, k8=(k>>3)&3, ko=k&7;  n' = 4h+g (f,i,o,c).
//     One (ntile,kt) block = 512 u16 = exactly one wave's 4-frag... no:
//     one wave-load: lane l reads 16B at l*8 -> fully coalesced 1KB.
// Region bias (blocks 8192..8207):  bias_il[4h+g] = b_g[h]
// ---------------------------------------------------------------------------
__global__ __launch_bounds__(256) void pack_all(
    const float* __restrict__ input, const float* __restrict__ hidden,
    const float* __restrict__ w_f, const float* __restrict__ w_i,
    const float* __restrict__ w_o, const float* __restrict__ w_c,
    const float* __restrict__ u_f, const float* __restrict__ u_i,
    const float* __restrict__ u_o, const float* __restrict__ u_c,
    const float* __restrict__ b1, const float* __restrict__ b2,
    const float* __restrict__ b3, const float* __restrict__ b4,
    u16* __restrict__ A, u16* __restrict__ Bf, float* __restrict__ bias_il) {
    __shared__ float tile[32][65];
    const int blk = blockIdx.x;
    const int t = threadIdx.x;

    if (blk < 4096) {
        // ---- pack_A ----
        int idx = (blk * 256 + t) * 4;
        int m = idx >> 11;
        int k = idx & (K_DIM - 1);
        const float* src = (k < H_DIM) ? (input + (size_t)m * H_DIM + k)
                                       : (hidden + (size_t)m * H_DIM + (k - H_DIM));
        float4 v = *(const float4*)src;
        ushort4 o;
        o.x = f2bf(v.x); o.y = f2bf(v.y); o.z = f2bf(v.z); o.w = f2bf(v.w);
        *(ushort4*)(A + idx) = o;
    } else if (blk < 8192) {
        // ---- pack_B: 32h x 64k tile transpose -> fragment-ready write ----
        int b2i = blk - 4096;
        int z = b2i >> 9;
        int rem = b2i & 511;
        int hx = rem & 31;
        int ky = rem >> 5;
        const float* M;
        switch (z) {
            case 0: M = w_f; break;
            case 1: M = w_i; break;
            case 2: M = w_o; break;
            case 3: M = w_c; break;
            case 4: M = u_f; break;
            case 5: M = u_i; break;
            case 6: M = u_o; break;
            default: M = u_c; break;
        }
        const int g = z & 3;
        const int half = z >> 2;
        const int h0 = hx * 32;
        const int k0 = ky * 64;
#pragma unroll
        for (int it = 0; it < 2; it++) {
            int kl = (t >> 3) + it * 32;
            int hl = (t & 7) * 4;
            float4 v = *(const float4*)(M + (size_t)(k0 + kl) * H_DIM + h0 + hl);
            tile[hl + 0][kl] = v.x;
            tile[hl + 1][kl] = v.y;
            tile[hl + 2][kl] = v.z;
            tile[hl + 3][kl] = v.w;
        }
        __syncthreads();
        int hl = t >> 3;
        int ko = (t & 7) * 8;             // 8-aligned k run of 8
        u16x8 o;
#pragma unroll
        for (int q = 0; q < 8; q++) o[q] = f2bf(tile[hl][ko + q]);
        size_t n = 4 * (size_t)(h0 + hl) + g;
        int kg = half * H_DIM + k0 + ko;  // global k (8-aligned)
        size_t ntile = n >> 4;
        int nrow = (int)(n & 15);
        int kt = kg >> 5;
        int k8 = (kg >> 3) & 3;
        *(u16x8*)(Bf + ((ntile * 64 + kt) * 64 + (k8 * 16 + nrow)) * 8) = o;
    } else {
        // ---- pack_bias ----
        int idx = (blk - 8192) * 256 + t;
        int h = idx >> 2, g = idx & 3;
        const float* b = (g == 0) ? b1 : (g == 1) ? b2 : (g == 2) ? b3 : b4;
        bias_il[idx] = b[h];
    }
}

// ---------------------------------------------------------------------------
// Kernel 2: fused GEMM + LSTM epilogue.
// R2 post-mortem: LDS pipe is the wall (768 cyc ds_read + 256 cyc staging
// per CU-KSTEP vs 155 cyc MFMA/SIMD).  R3: B LEAVES LDS -- fragment-packed
// Bf lets each wave load its 4 B-frags/KSTEP as coalesced 1KB
// global_load_dwordx4 straight to registers (2-KSTEP prefetch depth,
// double-buffered reg sets E/O).  LDS now carries only A: 4 ds_read + 8KB
// staging per block-KSTEP (half of R2).  A-path (4-slot ring, XOR swizzle,
// single barrier per KSTEP) unchanged from passing R2 kernel.
// vm stream per KSTEP is STRICTLY ORDERED (asm volatile + builtin can't
// cross asm "memory" fences): [2x A-stage(kt+3)] ... [4x B-load(kt+2)].
// Exact counted waits: A(kt) ready at vmcnt(16), B(kt) at vmcnt(8)
// (+sched_barrier(0) per rule #18); tail counts 14/8 and 6/4/0.
// ---------------------------------------------------------------------------
#define BM 128
#define BN 128

__global__ __launch_bounds__(256, 2) void gemm_fused(
    const u16* __restrict__ A, const u16* __restrict__ Bf,
    const float* __restrict__ bias_il, const float* __restrict__ pre_cell,
    const float* __restrict__ mask, float* __restrict__ out) {
    __shared__ char smem[32768];           // 4 A-slots x 8KB; epilogue et
    float* et = (float*)smem;              // epilogue reuse: [128][33] f32

    const int t = threadIdx.x;
    const int w = t >> 6, l = t & 63;
    const int m0 = blockIdx.y * BM;
    const int n0 = blockIdx.x * BN;
    const int wr = w >> 1;    // wave row in 2x2
    const int wc = w & 1;     // wave col
    const int lrow = l & 15;
    const int quad = l >> 4;

    // ---- A staging (pre-swizzled global source, linear LDS dest) ---------
    const int srow = t >> 2;                                // 0..63
    const int skswz = ((t & 3) * 8) ^ ((srow & 6) << 2);    // u16 units
    const u16* AgS0 = A + (size_t)(m0 + srow) * K_DIM + skswz;
    const u16* AgS1 = AgS0 + (size_t)64 * K_DIM;

    // ---- A fragment read offsets (rows + matching XOR) -------------------
    const int swzf = (quad * 8) ^ ((lrow & 6) << 2);        // u16 units
    const int foA = (wr * 64 + lrow) * 32 + swzf;

    // ---- B fragment global base: lane l reads 16B at block + l*8 ---------
    // frag j, tile kt: Bq + j*32768 + kt*512   (u16 units)
    const u16* Bq = Bf + ((size_t)(n0 >> 4) + wc * 4) * 32768 + (size_t)l * 8;

    // acc init = bias (constant down a column)
    f32x4 acc[4][4];
#pragma unroll
    for (int j = 0; j < 4; j++) {
        float bv = bias_il[n0 + wc * 64 + j * 16 + lrow];
#pragma unroll
        for (int i = 0; i < 4; i++) acc[i][j] = (f32x4){bv, bv, bv, bv};
    }
    // retire bias/scalar vector-loads so manual vmcnt counting is exact
    asm volatile("s_waitcnt vmcnt(0)" ::: "memory");

#define STAGEA(p)                                                           \
    {                                                                       \
        u16* As_ = (u16*)(smem + ((p) & 3) * 8192);                         \
        const int ko_ = (p) * 32;                                           \
        async16(AgS0 + ko_, As_ + t * 8);                                   \
        async16(AgS1 + ko_, As_ + 2048 + t * 8);                            \
    }

#define LOADB(reg, j, ktt)                                                  \
    asm volatile("global_load_dwordx4 %0, %1, off"                          \
                 : "=v"(reg)                                                \
                 : "v"(Bq + (size_t)(j) * 32768 + (size_t)(ktt) * 512)      \
                 : "memory");

    // ---- prologue: stage A0..A2, then load B(0)->E, B(1)->O --------------
    bf16x8 bE0, bE1, bE2, bE3, bO0, bO1, bO2, bO3;
    STAGEA(0); STAGEA(1); STAGEA(2);
    asm volatile("" ::: "memory");    // order: 6 A-stages before 8 B-loads
    LOADB(bE0, 0, 0); LOADB(bE1, 1, 0); LOADB(bE2, 2, 0); LOADB(bE3, 3, 0);
    LOADB(bO0, 0, 1); LOADB(bO1, 1, 1); LOADB(bO2, 2, 1); LOADB(bO3, 3, 1);

    // One KSTEP: wait A(kt) (counted vmcnt), publish barrier, stage A(kt+3),
    // ds_read 4 A-frags, wait B(kt) (counted vmcnt + sched_barrier), 16 MFMA,
    // then issue B(kt+2) into the just-consumed reg set (same parity).
#define KSTEP(kt, R0, R1, R2, R3, ACNT, BCNT, DOSTAGE, DOLOADB)             \
    {                                                                       \
        asm volatile("s_waitcnt vmcnt(" #ACNT ")" ::: "memory");            \
        __builtin_amdgcn_s_barrier();                                       \
        if (DOSTAGE) STAGEA((kt) + 3);                                      \
        const u16* As = (const u16*)(smem + ((kt) & 3) * 8192);             \
        bf16x8 af[4];                                                       \
        _Pragma("unroll") for (int i = 0; i < 4; i++)                       \
            af[i] = *(const bf16x8*)(As + foA + i * 512);                   \
        asm volatile("s_waitcnt vmcnt(" #BCNT ")" ::: "memory");            \
        __builtin_amdgcn_sched_barrier(0);                                  \
        __builtin_amdgcn_s_setprio(1);                                      \
        _Pragma("unroll") for (int i = 0; i < 4; i++) {                     \
            acc[i][0] = __builtin_amdgcn_mfma_f32_16x16x32_bf16(            \
                af[i], R0, acc[i][0], 0, 0, 0);                             \
            acc[i][1] = __builtin_amdgcn_mfma_f32_16x16x32_bf16(            \
                af[i], R1, acc[i][1], 0, 0, 0);                             \
            acc[i][2] = __builtin_amdgcn_mfma_f32_16x16x32_bf16(            \
                af[i], R2, acc[i][2], 0, 0, 0);                             \
            acc[i][3] = __builtin_amdgcn_mfma_f32_16x16x32_bf16(            \
                af[i], R3, acc[i][3], 0, 0, 0);                             \
        }                                                                   \
        __builtin_amdgcn_s_setprio(0);                                      \
        if (DOLOADB) {                                                      \
            LOADB(R0, 0, (kt) + 2); LOADB(R1, 1, (kt) + 2);                 \
            LOADB(R2, 2, (kt) + 2); LOADB(R3, 3, (kt) + 2);                 \
        }                                                                   \
        asm volatile("" ::: "memory");                                      \
    }

    // 64 K-tiles.  Steady state: per KSTEP 2 A-stage + 4 B-load ops.
    // A(kt)@kt-3: younger = B(kt-1):4 + 6 + 6 = 16.  B(kt)@kt-2 (last 4):
    // younger = 6 + same-KSTEP A-stage 2 = 8.  Startup/tail counts exact.
    KSTEP(0, bE0, bE1, bE2, bE3, 12, 6, 1, 1);
    KSTEP(1, bO0, bO1, bO2, bO3, 16, 8, 1, 1);
    for (int kt = 2; kt < 58; kt += 4) {
        KSTEP(kt + 0, bE0, bE1, bE2, bE3, 16, 8, 1, 1);
        KSTEP(kt + 1, bO0, bO1, bO2, bO3, 16, 8, 1, 1);
        KSTEP(kt + 2, bE0, bE1, bE2, bE3, 16, 8, 1, 1);
        KSTEP(kt + 3, bO0, bO1, bO2, bO3, 16, 8, 1, 1);
    }
    KSTEP(58, bE0, bE1, bE2, bE3, 16, 8, 1, 1);
    KSTEP(59, bO0, bO1, bO2, bO3, 16, 8, 1, 1);
    KSTEP(60, bE0, bE1, bE2, bE3, 16, 8, 1, 1);   // stages A(63), loads B(62)
    KSTEP(61, bO0, bO1, bO2, bO3, 16, 6, 0, 1);   // loads B(63)
    KSTEP(62, bE0, bE1, bE2, bE3, 14, 4, 0, 0);
    KSTEP(63, bO0, bO1, bO2, bO3,  8, 0, 0, 0);
#undef KSTEP
#undef STAGEA
#undef LOADB

    // ---- fused LSTM epilogue (unchanged, verified) ----
    // C/D layout: col = lane&15, row = quad*4 + reg  [m89/m91-verified]
    const int row = t >> 1;     // 0..127
    const int half = t & 1;     // 0 -> wc=0 cols, 1 -> wc=1 cols
    const size_t orow = (size_t)(m0 + row) * H_DIM;

    // prefetch epilogue operands now; latency hides under the 4 LDS phases
    float4 pc[4], mk[4];
#pragma unroll
    for (int j = 0; j < 4; j++) {
        const int hg0 = (n0 >> 2) + half * 16 + j * 4;
        pc[j] = *(const float4*)(pre_cell + orow + hg0);
        mk[j] = *(const float4*)(mask + orow + hg0);
    }

#pragma unroll
    for (int j = 0; j < 4; j++) {
        __syncthreads();        // et aliases staging; prior reads complete
#pragma unroll
        for (int i = 0; i < 4; i++)
#pragma unroll
            for (int r = 0; r < 4; r++)
                et[(wr * 64 + i * 16 + quad * 4 + r) * 33 + wc * 16 + lrow] =
                    acc[i][j][r];
        __syncthreads();
        const int hg0 = (n0 >> 2) + half * 16 + j * 4;
        const float* ep = et + row * 33 + half * 16;  // 4h x 4gates = 16 f32
        const float* ppc = (const float*)&pc[j];
        const float* pmk = (const float*)&mk[j];
        float4 oh, oc;
        float* poh = (float*)&oh;
        float* poc = (float*)&oc;
#pragma unroll
        for (int q = 0; q < 4; q++) {
            float fv = sigmoid_f(ep[4 * q + 0]);
            float iv = sigmoid_f(ep[4 * q + 1]);
            float ov = sigmoid_f(ep[4 * q + 2]);
            float gv = tanh_f(ep[4 * q + 3]);
            float cv = ppc[q] * fv + iv * gv;
            poc[q] = cv;
            poh[q] = ov * tanh_f(cv) * pmk[q];
        }
        *(float4*)(out + orow + hg0) = oh;
        *(float4*)(out + (size_t)B_DIM * H_DIM + orow + hg0) = oc;
    }
}

// ---------------------------------------------------------------------------
extern "C" void kernel_launch(void* const* d_in, const int* in_sizes, int n_in,
                              void* d_out, int out_size, void* d_ws, size_t ws_size,
                              hipStream_t stream) {
    const float* input    = (const float*)d_in[0];
    const float* hidden   = (const float*)d_in[1];
    const float* pre_cell = (const float*)d_in[2];
    const float* w_i = (const float*)d_in[3];
    const float* w_f = (const float*)d_in[4];
    const float* w_o = (const float*)d_in[5];
    const float* w_c = (const float*)d_in[6];
    const float* u_i = (const float*)d_in[7];
    const float* u_f = (const float*)d_in[8];
    const float* u_o = (const float*)d_in[9];
    const float* u_c = (const float*)d_in[10];
    const float* b1  = (const float*)d_in[11];
    const float* b2  = (const float*)d_in[12];
    const float* b3  = (const float*)d_in[13];
    const float* b4  = (const float*)d_in[14];
    const float* mask = (const float*)d_in[15];
    float* out = (float*)d_out;

    // workspace: A bf16 (8 MiB) | Bf bf16 frag-packed (16 MiB) | bias (16 KiB)
    char* ws = (char*)d_ws;
    u16*   A       = (u16*)ws;
    u16*   Bf      = (u16*)(ws + (size_t)8 * 1024 * 1024);
    float* bias_il = (float*)(ws + (size_t)24 * 1024 * 1024);

    pack_all<<<dim3(4096 + 4096 + 16), dim3(256), 0, stream>>>(
        input, hidden, w_f, w_i, w_o, w_c, u_f, u_i, u_o, u_c,
        b1, b2, b3, b4, A, Bf, bias_il);
    gemm_fused<<<dim3(N_DIM / BN, B_DIM / BM), dim3(256), 0, stream>>>(
        A, Bf, bias_il, pre_cell, mask, out);
}